// Round 1
// baseline (354.726 us; speedup 1.0000x reference)
//
#include <hip/hip_runtime.h>

// conv_transpose2d(x,(4,256,128,128), w(256,256,4,4) block-diagonal, stride=2)
// -> out (4,256,258,258). Depthwise: off-diagonal w entries are exactly 0.0,
// so summing only the diagonal channel is bit-identical to the dense conv.
// Filter values are still read from w (only sparsity structure is assumed).

#define CCH   256
#define HIN   128
#define WIN   128
#define HOUT  258
#define WOUT  258
#define CELLS 129   // 2x2 output cells per dim: ci in [0,128]

__global__ __launch_bounds__(256) void upconv2x_kernel(
    const float* __restrict__ x,
    const float* __restrict__ w,
    float* __restrict__ out)
{
    const int slice = blockIdx.y;            // n*CCH + c, 0..1023
    const int c = slice & (CCH - 1);

    __shared__ float f[16];                  // the 4x4 diagonal filter for c
    if (threadIdx.x < 16) {
        // w layout: (in=256, out=256, 4, 4); diagonal block at [c][c]
        f[threadIdx.x] = w[((size_t)c * CCH + c) * 16 + threadIdx.x];
    }
    __syncthreads();

    const int t = blockIdx.x * blockDim.x + threadIdx.x;
    if (t >= CELLS * CELLS) return;
    const int ci = t / CELLS;                // cell row: output rows 2ci, 2ci+1
    const int cj = t - ci * CELLS;           // cell col: output cols 2cj, 2cj+1

    // out[2ci+dh][2cj+dw] = sum_{a,b in {0,1}} x[ci-a][cj-b] * f[dh+2a][dw+2b]
    const float* xs = x + (size_t)slice * (HIN * WIN);
    const bool r0 = (ci < HIN);              // row ci valid
    const bool r1 = (ci > 0);                // row ci-1 valid
    const bool c0 = (cj < WIN);              // col cj valid
    const bool c1 = (cj > 0);                // col cj-1 valid

    const float x00 = (r0 && c0) ? xs[(size_t)ci * WIN + cj]           : 0.f;
    const float x01 = (r0 && c1) ? xs[(size_t)ci * WIN + cj - 1]       : 0.f;
    const float x10 = (r1 && c0) ? xs[(size_t)(ci - 1) * WIN + cj]     : 0.f;
    const float x11 = (r1 && c1) ? xs[(size_t)(ci - 1) * WIN + cj - 1] : 0.f;

    float o[2][2];
#pragma unroll
    for (int dh = 0; dh < 2; ++dh) {
#pragma unroll
        for (int dw = 0; dw < 2; ++dw) {
            o[dh][dw] = x00 * f[dh * 4 + dw]
                      + x01 * f[dh * 4 + dw + 2]
                      + x10 * f[(dh + 2) * 4 + dw]
                      + x11 * f[(dh + 2) * 4 + dw + 2];
        }
    }

    float* os = out + (size_t)slice * (HOUT * WOUT);
    const int oh = 2 * ci, ow = 2 * cj;
    // 8B-aligned: slice*66564, oh*258, ow are all even element offsets
    *(float2*)(os + (size_t)oh * WOUT + ow)       = make_float2(o[0][0], o[0][1]);
    *(float2*)(os + (size_t)(oh + 1) * WOUT + ow) = make_float2(o[1][0], o[1][1]);
}

extern "C" void kernel_launch(void* const* d_in, const int* in_sizes, int n_in,
                              void* d_out, int out_size, void* d_ws, size_t ws_size,
                              hipStream_t stream) {
    const float* x = (const float*)d_in[0];
    const float* w = (const float*)d_in[1];
    float* out = (float*)d_out;

    const int cells = CELLS * CELLS;                 // 16641
    dim3 block(256);
    dim3 grid((cells + 255) / 256, 4 * CCH);         // 66 x 1024
    upconv2x_kernel<<<grid, block, 0, stream>>>(x, w, out);
}

// Round 2
// 354.116 us; speedup vs baseline: 1.0017x; 1.0017x over previous
//
#include <hip/hip_runtime.h>

// conv_transpose2d(x(4,256,128,128), w(256,256,4,4) block-diagonal, stride=2)
// -> out (4,256,258,258). Depthwise: off-diagonal w entries are exactly 0.0,
// so using only w[c][c] is bit-identical to the dense conv.
//
// R2 design: one thread computes a 2-row x 8-col output tile (one cell-row,
// 4 cells). Filter w[c][c] is loaded with uniform (blockIdx-only) indices ->
// compiler emits s_load into SGPRs: no LDS, no __syncthreads. x loads are
// float4 + one halo scalar per row, edges handled by clamp+select (branchless).
// Even output rows are 16B-aligned (row pitch 258 floats => odd rows are only
// 8B-aligned, stored as float2/float4/float2).

#define CCH   256
#define HIN   128
#define WIN   128
#define HOUT  258
#define WOUT  258
#define CELLS 129            // cell ci/cj in [0,128]; out rows 2ci,2ci+1
#define GRP   33             // groups of 4 cells per cell-row (last has 1 cell)

__global__ __launch_bounds__(256) void upconv2x_kernel(
    const float* __restrict__ x,
    const float* __restrict__ w,
    float* __restrict__ out)
{
    const int slice = blockIdx.y;           // n*CCH + c
    const int c = slice & (CCH - 1);

    // Uniform index -> scalar loads into SGPRs (no LDS, no sync)
    const float* __restrict__ wf = w + ((size_t)c * CCH + c) * 16;
    float f[16];
#pragma unroll
    for (int i = 0; i < 16; ++i) f[i] = wf[i];

    const int t = blockIdx.x * blockDim.x + threadIdx.x;
    if (t >= CELLS * GRP) return;
    const int ci  = t / GRP;
    const int g   = t - ci * GRP;
    const int cj0 = g * 4;                  // first cell col of this group

    // x rows needed: ci (row0) and ci-1 (row1); cols cj0-1 .. cj0+3
    const bool rv0 = (ci < HIN);
    const bool rv1 = (ci > 0);
    const bool g32 = (cj0 == 128);          // tail group: single cell cj=128
    const int  iy0 = rv0 ? ci : (HIN - 1);
    const int  iy1 = rv1 ? (ci - 1) : 0;
    const int  cjc = g32 ? 124 : cj0;       // keep float4 load in-bounds
    const int  hj  = (cj0 > 0) ? (cj0 - 1) : 0;

    const float* __restrict__ xs = x + (size_t)slice * (HIN * WIN);
    const float* __restrict__ b0 = xs + (size_t)iy0 * WIN;
    const float* __restrict__ b1 = xs + (size_t)iy1 * WIN;

    float4 a0 = *(const float4*)(b0 + cjc);
    float4 a1 = *(const float4*)(b1 + cjc);
    float  h0 = b0[hj];
    float  h1 = b1[hj];

    if (!rv0 ) { a0 = make_float4(0.f,0.f,0.f,0.f); h0 = 0.f; }
    if (!rv1 ) { a1 = make_float4(0.f,0.f,0.f,0.f); h1 = 0.f; }
    if (g32  ) { a0 = make_float4(0.f,0.f,0.f,0.f);
                 a1 = make_float4(0.f,0.f,0.f,0.f); }
    if (cj0 == 0) { h0 = 0.f; h1 = 0.f; }

    // cols cj0-1..cj0+3 for both rows
    const float c0[5] = { h0, a0.x, a0.y, a0.z, a0.w };
    const float c1[5] = { h1, a1.x, a1.y, a1.z, a1.w };

    // out[2ci+dh][2(cj0+k)+dw] = x00*f[4dh+dw] + x01*f[4dh+dw+2]
    //                          + x10*f[4dh+8+dw] + x11*f[4dh+8+dw+2]
    // with x00=c0[k+1], x01=c0[k], x10=c1[k+1], x11=c1[k]
    float e[8], o[8];
#pragma unroll
    for (int k = 0; k < 4; ++k) {
        const float p0 = c0[k + 1], m0 = c0[k];
        const float p1 = c1[k + 1], m1 = c1[k];
        e[2*k]   = p0*f[0] + m0*f[2]  + p1*f[8]  + m1*f[10];
        e[2*k+1] = p0*f[1] + m0*f[3]  + p1*f[9]  + m1*f[11];
        o[2*k]   = p0*f[4] + m0*f[6]  + p1*f[12] + m1*f[14];
        o[2*k+1] = p0*f[5] + m0*f[7]  + p1*f[13] + m1*f[15];
    }

    float* __restrict__ os = out + (size_t)slice * (HOUT * WOUT);
    float* pe = os + (size_t)(2 * ci) * WOUT + 2 * cj0;  // 16B-aligned
    float* po = pe + WOUT;                               // 8B-aligned only

    if (!g32) {
        *(float4*)(pe)     = make_float4(e[0], e[1], e[2], e[3]);
        *(float4*)(pe + 4) = make_float4(e[4], e[5], e[6], e[7]);
        *(float2*)(po)     = make_float2(o[0], o[1]);
        *(float4*)(po + 2) = make_float4(o[2], o[3], o[4], o[5]);
        *(float2*)(po + 6) = make_float2(o[6], o[7]);
    } else {
        // tail: only cell cj=128 -> out cols 256,257
        *(float2*)(pe) = make_float2(e[0], e[1]);
        *(float2*)(po) = make_float2(o[0], o[1]);
    }
}

extern "C" void kernel_launch(void* const* d_in, const int* in_sizes, int n_in,
                              void* d_out, int out_size, void* d_ws, size_t ws_size,
                              hipStream_t stream) {
    const float* x = (const float*)d_in[0];
    const float* w = (const float*)d_in[1];
    float* out = (float*)d_out;

    const int work = CELLS * GRP;                    // 4257 threads per slice
    dim3 block(256);
    dim3 grid((work + 255) / 256, 4 * CCH);          // 17 x 1024
    upconv2x_kernel<<<grid, block, 0, stream>>>(x, w, out);
}